// Round 1
// baseline (3105.460 us; speedup 1.0000x reference)
//
#include <hip/hip_runtime.h>
#include <math.h>

// Problem constants (fixed by the reference setup)
#define BATCH  128
#define NENT   256
#define INDIM  256
#define HID    512
#define NHEAD  8
#define NAGENT 64
#define SCALE  0.04419417382415922f   // 1/sqrt(512)

__device__ __forceinline__ void fma4(float4& d, float s, const float4& b) {
    d.x = fmaf(s, b.x, d.x);
    d.y = fmaf(s, b.y, d.y);
    d.z = fmaf(s, b.z, d.z);
    d.w = fmaf(s, b.w, d.w);
}
__device__ __forceinline__ float dot4acc(float acc, const float4& a, const float4& b) {
    acc = fmaf(a.x, b.x, acc);
    acc = fmaf(a.y, b.y, acc);
    acc = fmaf(a.z, b.z, acc);
    acc = fmaf(a.w, b.w, acc);
    return acc;
}
__device__ __forceinline__ float4 zero4() { return make_float4(0.f, 0.f, 0.f, 0.f); }

// -----------------------------------------------------------------------------
// K1: h[32768][512] = leaky_relu(x[32768][256]) @ W_enc[256][512] + b_enc
// Block: 16 rows x 256 cols tile. grid = 2048 row-tiles x 2 col-chunks = 4096.
// A (lrelu'd x tile) staged in LDS, broadcast reads; B streamed coalesced f4.
// -----------------------------------------------------------------------------
__global__ __launch_bounds__(256) void enc_kernel(const float* __restrict__ x,
                                                  const float* __restrict__ W,
                                                  const float* __restrict__ bias,
                                                  float* __restrict__ h) {
    __shared__ float xa[16][INDIM];
    const int bid = blockIdx.x;
    const int cc  = (bid & 1) * 256;
    const int r0  = (bid >> 1) * 16;
    const int t   = threadIdx.x;

    // stage leaky_relu(x) tile: 16x256 floats, coalesced float4 loads
    #pragma unroll
    for (int l = 0; l < 4; ++l) {
        int fid = t + 256 * l;          // float4 id; 64 float4 per row
        int row = fid >> 6;
        int c4  = (fid & 63) * 4;
        float4 v = *(const float4*)(x + (size_t)(r0 + row) * INDIM + c4);
        v.x = v.x > 0.f ? v.x : 0.01f * v.x;
        v.y = v.y > 0.f ? v.y : 0.01f * v.y;
        v.z = v.z > 0.f ? v.z : 0.01f * v.z;
        v.w = v.w > 0.f ? v.w : 0.01f * v.w;
        *(float4*)&xa[row][c4] = v;
    }
    __syncthreads();

    const int tx = t & 63, ty = t >> 6;
    const int c  = cc + tx * 4;
    float4 acc[4] = {zero4(), zero4(), zero4(), zero4()};

    for (int kt = 0; kt < INDIM; kt += 4) {
        float4 a[4];
        #pragma unroll
        for (int j = 0; j < 4; ++j) a[j] = *(const float4*)&xa[ty + 4 * j][kt];
        float4 b0 = *(const float4*)(W + (size_t)(kt + 0) * HID + c);
        float4 b1 = *(const float4*)(W + (size_t)(kt + 1) * HID + c);
        float4 b2 = *(const float4*)(W + (size_t)(kt + 2) * HID + c);
        float4 b3 = *(const float4*)(W + (size_t)(kt + 3) * HID + c);
        #pragma unroll
        for (int j = 0; j < 4; ++j) {
            fma4(acc[j], a[j].x, b0);
            fma4(acc[j], a[j].y, b1);
            fma4(acc[j], a[j].z, b2);
            fma4(acc[j], a[j].w, b3);
        }
    }
    float4 bv = *(const float4*)(bias + c);
    #pragma unroll
    for (int j = 0; j < 4; ++j) {
        float4 r = acc[j];
        r.x += bv.x; r.y += bv.y; r.z += bv.z; r.w += bv.w;
        *(float4*)(h + (size_t)(r0 + ty + 4 * j) * HID + c) = r;
    }
}

// -----------------------------------------------------------------------------
// K2: M[n][i][j] = SCALE * sum_k WQ[n][i][k] * WK[n][j][k]   (8 x 512 x 512)
// Block: 64x64 tile, per-thread 4x4, both operands are row-walks (L1-resident).
// grid = 8 * 8 * 8 = 512 blocks.
// -----------------------------------------------------------------------------
__global__ __launch_bounds__(256) void wqk_kernel(const float* __restrict__ WQ,
                                                  const float* __restrict__ WK,
                                                  float* __restrict__ M) {
    const int bid = blockIdx.x;
    const int jt  = (bid & 7) * 64;
    const int it  = ((bid >> 3) & 7) * 64;
    const int n   = bid >> 6;
    const float* q = WQ + (size_t)n * HID * HID;
    const float* k = WK + (size_t)n * HID * HID;
    const int t  = threadIdx.x;
    const int jj = jt + (t & 15) * 4;
    const int ii = it + (t >> 4) * 4;

    float4 acc[4] = {zero4(), zero4(), zero4(), zero4()};   // acc[i] over 4 j's
    for (int kt = 0; kt < HID; kt += 4) {
        float4 a[4], b[4];
        #pragma unroll
        for (int i = 0; i < 4; ++i) a[i] = *(const float4*)(q + (size_t)(ii + i) * HID + kt);
        #pragma unroll
        for (int j = 0; j < 4; ++j) b[j] = *(const float4*)(k + (size_t)(jj + j) * HID + kt);
        #pragma unroll
        for (int i = 0; i < 4; ++i) {
            acc[i].x = dot4acc(acc[i].x, a[i], b[0]);
            acc[i].y = dot4acc(acc[i].y, a[i], b[1]);
            acc[i].z = dot4acc(acc[i].z, a[i], b[2]);
            acc[i].w = dot4acc(acc[i].w, a[i], b[3]);
        }
    }
    #pragma unroll
    for (int i = 0; i < 4; ++i) {
        float4 r = acc[i];
        r.x *= SCALE; r.y *= SCALE; r.z *= SCALE; r.w *= SCALE;
        *(float4*)(M + (size_t)n * HID * HID + (size_t)(ii + i) * HID + jj) = r;
    }
}

// -----------------------------------------------------------------------------
// K3: fused attention. One block per (head n, batch b, 16-agent tile).
// Phases: T = ha@M  ->  S = T@h^T  ->  softmax(S)  ->  U = P@h  ->  z = U@WV
// out[b,a,:] += z/8 via atomicAdd (8 heads reduce).
// LDS: TU 32KB (T, then reused for U) + S 16KB + red ~1KB  = ~50KB.
// grid = 8 * 128 * 4 = 4096 blocks.
// -----------------------------------------------------------------------------
__global__ __launch_bounds__(256) void attn_kernel(const float* __restrict__ h,
                                                   const float* __restrict__ M,
                                                   const float* __restrict__ WV,
                                                   float* __restrict__ out) {
    __shared__ float TU[16][HID];     // 32 KB: T in phases A/B, U in phases C/D
    __shared__ float S[16][NENT];     // 16 KB: scores -> probabilities
    __shared__ float red[16][17];     // softmax reduction scratch

    const int bid = blockIdx.x;
    const int at  = (bid & 3) * 16;
    const int b   = (bid >> 2) & 127;
    const int n   = bid >> 9;
    const int t   = threadIdx.x;
    const int tx  = t & 63, ty = t >> 6;

    const float* hb = h + (size_t)b * NENT * HID;
    const float* ha = hb + (size_t)at * HID;               // agents = first 64 entities
    const float* Mn = M + (size_t)n * HID * HID;
    const float* Vn = WV + (size_t)n * HID * HID;

    // ---- Phase A: T(16x512) = ha(16x512) @ M(512x512) ----
    for (int cc = 0; cc < HID; cc += 256) {
        const int c = cc + tx * 4;
        float4 acc[4] = {zero4(), zero4(), zero4(), zero4()};
        for (int kt = 0; kt < HID; kt += 4) {
            float4 a[4];
            #pragma unroll
            for (int j = 0; j < 4; ++j)
                a[j] = *(const float4*)(ha + (size_t)(ty + 4 * j) * HID + kt);  // broadcast
            float4 b0 = *(const float4*)(Mn + (size_t)(kt + 0) * HID + c);
            float4 b1 = *(const float4*)(Mn + (size_t)(kt + 1) * HID + c);
            float4 b2 = *(const float4*)(Mn + (size_t)(kt + 2) * HID + c);
            float4 b3 = *(const float4*)(Mn + (size_t)(kt + 3) * HID + c);
            #pragma unroll
            for (int j = 0; j < 4; ++j) {
                fma4(acc[j], a[j].x, b0);
                fma4(acc[j], a[j].y, b1);
                fma4(acc[j], a[j].z, b2);
                fma4(acc[j], a[j].w, b3);
            }
        }
        #pragma unroll
        for (int j = 0; j < 4; ++j) *(float4*)&TU[ty + 4 * j][c] = acc[j];
    }
    __syncthreads();

    // ---- Phase B: S(16x256) = T(16x512) @ hb^T ----
    {
        const int e0 = tx * 4;
        float4 accB[4] = {zero4(), zero4(), zero4(), zero4()};  // [row j], comps = 4 e's
        for (int kt = 0; kt < HID; kt += 4) {
            float4 a[4];
            #pragma unroll
            for (int j = 0; j < 4; ++j) a[j] = *(const float4*)&TU[ty + 4 * j][kt];
            float4 bv0 = *(const float4*)(hb + (size_t)(e0 + 0) * HID + kt);
            float4 bv1 = *(const float4*)(hb + (size_t)(e0 + 1) * HID + kt);
            float4 bv2 = *(const float4*)(hb + (size_t)(e0 + 2) * HID + kt);
            float4 bv3 = *(const float4*)(hb + (size_t)(e0 + 3) * HID + kt);
            #pragma unroll
            for (int j = 0; j < 4; ++j) {
                accB[j].x = dot4acc(accB[j].x, a[j], bv0);
                accB[j].y = dot4acc(accB[j].y, a[j], bv1);
                accB[j].z = dot4acc(accB[j].z, a[j], bv2);
                accB[j].w = dot4acc(accB[j].w, a[j], bv3);
            }
        }
        #pragma unroll
        for (int j = 0; j < 4; ++j) *(float4*)&S[ty + 4 * j][e0] = accB[j];
    }
    __syncthreads();

    // ---- Softmax over rows of S (ref: softmax then /(sum+1e-12) ~= softmax) ----
    {
        const int row = t >> 4, g = t & 15;
        float lmax = -3.4e38f;
        #pragma unroll
        for (int m = 0; m < 16; ++m) lmax = fmaxf(lmax, S[row][g + 16 * m]);
        red[row][g] = lmax;
        __syncthreads();
        if (g == 0) {
            float mx = red[row][0];
            #pragma unroll
            for (int m = 1; m < 16; ++m) mx = fmaxf(mx, red[row][m]);
            red[row][16] = mx;
        }
        __syncthreads();
        const float mx = red[row][16];
        float lsum = 0.f;
        #pragma unroll
        for (int m = 0; m < 16; ++m) {
            float p = __expf(S[row][g + 16 * m] - mx);
            S[row][g + 16 * m] = p;
            lsum += p;
        }
        red[row][g] = lsum;
        __syncthreads();
        if (g == 0) {
            float s = 0.f;
            #pragma unroll
            for (int m = 0; m < 16; ++m) s += red[row][m];
            red[row][16] = 1.0f / s;
        }
        __syncthreads();
        const float inv = red[row][16];
        #pragma unroll
        for (int m = 0; m < 16; ++m) S[row][g + 16 * m] *= inv;
    }
    __syncthreads();

    // ---- Phase C: U(16x512) = P(16x256) @ hb(256x512), overwrite TU ----
    for (int cc = 0; cc < HID; cc += 256) {
        const int c = cc + tx * 4;
        float4 acc[4] = {zero4(), zero4(), zero4(), zero4()};
        for (int kt = 0; kt < NENT; kt += 4) {
            float4 a[4];
            #pragma unroll
            for (int j = 0; j < 4; ++j) a[j] = *(const float4*)&S[ty + 4 * j][kt];
            float4 b0 = *(const float4*)(hb + (size_t)(kt + 0) * HID + c);
            float4 b1 = *(const float4*)(hb + (size_t)(kt + 1) * HID + c);
            float4 b2 = *(const float4*)(hb + (size_t)(kt + 2) * HID + c);
            float4 b3 = *(const float4*)(hb + (size_t)(kt + 3) * HID + c);
            #pragma unroll
            for (int j = 0; j < 4; ++j) {
                fma4(acc[j], a[j].x, b0);
                fma4(acc[j], a[j].y, b1);
                fma4(acc[j], a[j].z, b2);
                fma4(acc[j], a[j].w, b3);
            }
        }
        #pragma unroll
        for (int j = 0; j < 4; ++j) *(float4*)&TU[ty + 4 * j][c] = acc[j];
    }
    __syncthreads();

    // ---- Phase D: z(16x512) = U(16x512) @ WV_n(512x512); out += z/8 ----
    float* ob = out + ((size_t)b * NAGENT + at) * HID;
    for (int cc = 0; cc < HID; cc += 256) {
        const int c = cc + tx * 4;
        float4 acc[4] = {zero4(), zero4(), zero4(), zero4()};
        for (int kt = 0; kt < HID; kt += 4) {
            float4 a[4];
            #pragma unroll
            for (int j = 0; j < 4; ++j) a[j] = *(const float4*)&TU[ty + 4 * j][kt];
            float4 b0 = *(const float4*)(Vn + (size_t)(kt + 0) * HID + c);
            float4 b1 = *(const float4*)(Vn + (size_t)(kt + 1) * HID + c);
            float4 b2 = *(const float4*)(Vn + (size_t)(kt + 2) * HID + c);
            float4 b3 = *(const float4*)(Vn + (size_t)(kt + 3) * HID + c);
            #pragma unroll
            for (int j = 0; j < 4; ++j) {
                fma4(acc[j], a[j].x, b0);
                fma4(acc[j], a[j].y, b1);
                fma4(acc[j], a[j].z, b2);
                fma4(acc[j], a[j].w, b3);
            }
        }
        #pragma unroll
        for (int j = 0; j < 4; ++j) {
            float* p = ob + (size_t)(ty + 4 * j) * HID + c;
            atomicAdd(p + 0, acc[j].x * 0.125f);
            atomicAdd(p + 1, acc[j].y * 0.125f);
            atomicAdd(p + 2, acc[j].z * 0.125f);
            atomicAdd(p + 3, acc[j].w * 0.125f);
        }
    }
}

// -----------------------------------------------------------------------------
// Launch. ws layout: h (32768*512*4 = 64MB) | M (8*512*512*4 = 8MB) = 72MB.
// n_agents (d_in[6]) is fixed at 64 by the problem; hard-coded.
// -----------------------------------------------------------------------------
extern "C" void kernel_launch(void* const* d_in, const int* in_sizes, int n_in,
                              void* d_out, int out_size, void* d_ws, size_t ws_size,
                              hipStream_t stream) {
    const float* x     = (const float*)d_in[0];
    const float* W_enc = (const float*)d_in[1];
    const float* b_enc = (const float*)d_in[2];
    const float* WQ    = (const float*)d_in[3];
    const float* WK    = (const float*)d_in[4];
    const float* WV    = (const float*)d_in[5];
    float* out = (float*)d_out;

    float* h = (float*)d_ws;                                   // 64 MB
    float* M = (float*)((char*)d_ws + (size_t)32768 * HID * 4); // 8 MB

    hipMemsetAsync(d_out, 0, (size_t)out_size * sizeof(float), stream);
    enc_kernel<<<4096, 256, 0, stream>>>(x, W_enc, b_enc, h);
    wqk_kernel<<<512, 256, 0, stream>>>(WQ, WK, M);
    attn_kernel<<<4096, 256, 0, stream>>>(h, M, WV, out);
}

// Round 2
// 1114.403 us; speedup vs baseline: 2.7867x; 2.7867x over previous
//
#include <hip/hip_runtime.h>
#include <math.h>

#define BATCH  128
#define NENT   256
#define INDIM  256
#define HID    512
#define NHEAD  8
#define NAGENT 64
#define SCALE  0.04419417382415922f   // 1/sqrt(512)

typedef unsigned short u16;
typedef unsigned int   u32;

typedef __bf16 bf16x8  __attribute__((ext_vector_type(8)));
typedef float  floatx4 __attribute__((ext_vector_type(4)));
typedef u32    u32x4   __attribute__((ext_vector_type(4)));
typedef u32    u32x2   __attribute__((ext_vector_type(2)));

union Frag {
    u32x4 s;
    struct { u32x2 lo, hi; } p;
    bf16x8 v;
};

__device__ __forceinline__ u16 f2bf(float x) {
    u32 u = __float_as_uint(x);
    return (u16)((u + 0x7FFFu + ((u >> 16) & 1u)) >> 16);
}
__device__ __forceinline__ float bf2f(u16 b) {
    return __uint_as_float(((u32)b) << 16);
}
__device__ __forceinline__ float dot4acc(float acc, const float4& a, const float4& b) {
    acc = fmaf(a.x, b.x, acc); acc = fmaf(a.y, b.y, acc);
    acc = fmaf(a.z, b.z, acc); acc = fmaf(a.w, b.w, acc);
    return acc;
}

// -----------------------------------------------------------------------------
// K1: h = leaky_relu(x) @ W_enc + b_enc  -> bf16 hi/lo pair (row-major [row][512])
// -----------------------------------------------------------------------------
__global__ __launch_bounds__(256) void enc_kernel(const float* __restrict__ x,
                                                  const float* __restrict__ W,
                                                  const float* __restrict__ bias,
                                                  u16* __restrict__ h_h,
                                                  u16* __restrict__ h_l) {
    __shared__ float xa[16][INDIM];
    const int bid = blockIdx.x;
    const int cc  = (bid & 1) * 256;
    const int r0  = (bid >> 1) * 16;
    const int t   = threadIdx.x;

    #pragma unroll
    for (int l = 0; l < 4; ++l) {
        int fid = t + 256 * l;
        int row = fid >> 6;
        int c4  = (fid & 63) * 4;
        float4 v = *(const float4*)(x + (size_t)(r0 + row) * INDIM + c4);
        v.x = v.x > 0.f ? v.x : 0.01f * v.x;
        v.y = v.y > 0.f ? v.y : 0.01f * v.y;
        v.z = v.z > 0.f ? v.z : 0.01f * v.z;
        v.w = v.w > 0.f ? v.w : 0.01f * v.w;
        *(float4*)&xa[row][c4] = v;
    }
    __syncthreads();

    const int tx = t & 63, ty = t >> 6;
    const int c  = cc + tx * 4;
    float4 acc[4];
    #pragma unroll
    for (int j = 0; j < 4; ++j) acc[j] = make_float4(0.f, 0.f, 0.f, 0.f);

    for (int kt = 0; kt < INDIM; kt += 4) {
        float4 a[4];
        #pragma unroll
        for (int j = 0; j < 4; ++j) a[j] = *(const float4*)&xa[ty + 4 * j][kt];
        float4 b0 = *(const float4*)(W + (size_t)(kt + 0) * HID + c);
        float4 b1 = *(const float4*)(W + (size_t)(kt + 1) * HID + c);
        float4 b2 = *(const float4*)(W + (size_t)(kt + 2) * HID + c);
        float4 b3 = *(const float4*)(W + (size_t)(kt + 3) * HID + c);
        #pragma unroll
        for (int j = 0; j < 4; ++j) {
            acc[j].x = fmaf(a[j].x, b0.x, acc[j].x); acc[j].y = fmaf(a[j].x, b0.y, acc[j].y);
            acc[j].z = fmaf(a[j].x, b0.z, acc[j].z); acc[j].w = fmaf(a[j].x, b0.w, acc[j].w);
            acc[j].x = fmaf(a[j].y, b1.x, acc[j].x); acc[j].y = fmaf(a[j].y, b1.y, acc[j].y);
            acc[j].z = fmaf(a[j].y, b1.z, acc[j].z); acc[j].w = fmaf(a[j].y, b1.w, acc[j].w);
            acc[j].x = fmaf(a[j].z, b2.x, acc[j].x); acc[j].y = fmaf(a[j].z, b2.y, acc[j].y);
            acc[j].z = fmaf(a[j].z, b2.z, acc[j].z); acc[j].w = fmaf(a[j].z, b2.w, acc[j].w);
            acc[j].x = fmaf(a[j].w, b3.x, acc[j].x); acc[j].y = fmaf(a[j].w, b3.y, acc[j].y);
            acc[j].z = fmaf(a[j].w, b3.z, acc[j].z); acc[j].w = fmaf(a[j].w, b3.w, acc[j].w);
        }
    }
    float4 bv = *(const float4*)(bias + c);
    #pragma unroll
    for (int j = 0; j < 4; ++j) {
        float4 r = acc[j];
        r.x += bv.x; r.y += bv.y; r.z += bv.z; r.w += bv.w;
        ushort4 hh, hl;
        hh.x = f2bf(r.x); hl.x = f2bf(r.x - bf2f(hh.x));
        hh.y = f2bf(r.y); hl.y = f2bf(r.y - bf2f(hh.y));
        hh.z = f2bf(r.z); hl.z = f2bf(r.z - bf2f(hh.z));
        hh.w = f2bf(r.w); hl.w = f2bf(r.w - bf2f(hh.w));
        size_t o = (size_t)(r0 + ty + 4 * j) * HID + c;
        *(ushort4*)(h_h + o) = hh;
        *(ushort4*)(h_l + o) = hl;
    }
}

// -----------------------------------------------------------------------------
// K2: Mt[n][j][i] = SCALE * dot(WQ[n][i,:], WK[n][j,:])   (transposed M, hi/lo)
// -----------------------------------------------------------------------------
__global__ __launch_bounds__(256) void wqk_kernel(const float* __restrict__ WQ,
                                                  const float* __restrict__ WK,
                                                  u16* __restrict__ Mt_h,
                                                  u16* __restrict__ Mt_l) {
    const int bid = blockIdx.x;
    const int it = (bid & 7) * 64;
    const int jt = ((bid >> 3) & 7) * 64;
    const int n  = bid >> 6;
    const float* q  = WQ + (size_t)n * HID * HID;
    const float* kk = WK + (size_t)n * HID * HID;
    const int t  = threadIdx.x;
    const int ii = it + (t & 15) * 4;
    const int jj = jt + (t >> 4) * 4;

    float4 acc[4];   // acc[jr], components over 4 i's
    #pragma unroll
    for (int j = 0; j < 4; ++j) acc[j] = make_float4(0.f, 0.f, 0.f, 0.f);
    for (int kt = 0; kt < HID; kt += 4) {
        float4 a[4], bb[4];
        #pragma unroll
        for (int jr = 0; jr < 4; ++jr) a[jr] = *(const float4*)(kk + (size_t)(jj + jr) * HID + kt);
        #pragma unroll
        for (int ic = 0; ic < 4; ++ic) bb[ic] = *(const float4*)(q + (size_t)(ii + ic) * HID + kt);
        #pragma unroll
        for (int jr = 0; jr < 4; ++jr) {
            acc[jr].x = dot4acc(acc[jr].x, a[jr], bb[0]);
            acc[jr].y = dot4acc(acc[jr].y, a[jr], bb[1]);
            acc[jr].z = dot4acc(acc[jr].z, a[jr], bb[2]);
            acc[jr].w = dot4acc(acc[jr].w, a[jr], bb[3]);
        }
    }
    #pragma unroll
    for (int jr = 0; jr < 4; ++jr) {
        float4 r = acc[jr];
        r.x *= SCALE; r.y *= SCALE; r.z *= SCALE; r.w *= SCALE;
        ushort4 hh, hl;
        hh.x = f2bf(r.x); hl.x = f2bf(r.x - bf2f(hh.x));
        hh.y = f2bf(r.y); hl.y = f2bf(r.y - bf2f(hh.y));
        hh.z = f2bf(r.z); hl.z = f2bf(r.z - bf2f(hh.z));
        hh.w = f2bf(r.w); hl.w = f2bf(r.w - bf2f(hh.w));
        size_t o = (size_t)n * 262144 + (size_t)(jj + jr) * HID + ii;
        *(ushort4*)(Mt_h + o) = hh;
        *(ushort4*)(Mt_l + o) = hl;
    }
}

// -----------------------------------------------------------------------------
// K3: WVt[n][dout][din] = bf16(WV[n][din][dout])  (value path: hi only)
// -----------------------------------------------------------------------------
__global__ __launch_bounds__(256) void wvt_kernel(const float* __restrict__ WV,
                                                  u16* __restrict__ WVt) {
    __shared__ float tile[64][68];
    const int bid = blockIdx.x;
    const int i0 = (bid & 7) * 64;          // din tile
    const int o0 = ((bid >> 3) & 7) * 64;   // dout tile
    const int n  = bid >> 6;
    const float* src = WV + (size_t)n * 262144;
    const int t  = threadIdx.x;
    const int di = t >> 2;
    const int dc = (t & 3) * 16;
    #pragma unroll
    for (int c = 0; c < 4; ++c) {
        float4 v = *(const float4*)(src + (size_t)(i0 + di) * HID + o0 + dc + c * 4);
        *(float4*)&tile[di][dc + c * 4] = v;
    }
    __syncthreads();
    const int dr = t >> 2;
    const int ic = (t & 3) * 16;
    u16 tmp[16];
    #pragma unroll
    for (int m = 0; m < 16; ++m) tmp[m] = f2bf(tile[ic + m][dr]);
    size_t o = (size_t)n * 262144 + (size_t)(o0 + dr) * HID + i0 + ic;
    #pragma unroll
    for (int c = 0; c < 4; ++c) {
        ushort4 v = make_ushort4(tmp[c * 4], tmp[c * 4 + 1], tmp[c * 4 + 2], tmp[c * 4 + 3]);
        *(ushort4*)(WVt + o + c * 4) = v;
    }
}

// -----------------------------------------------------------------------------
// K4: fused MFMA attention. Block = (head n, batch b, 32-agent tile at).
// Phases: A: T=ha@Mt (split, 3-pass) -> Th/Tl LDS (two 256-col halves)
//         B: S^T = hb@T^T (split, 3-pass), S-acc persists across halves
//         softmax -> Pt bf16 [a][e]
//         C: U = P@hb, hb^T staged per-wave in LDS, plain bf16
//         D: z = U@WVt, plain bf16; atomicAdd out (8 heads reduce), *0.125
// LDS regions (54528 B total, 3 blocks/CU):
//   [0,36864): Th[32][260]+Tl -> S[256][32] f32 -> HbT[512][36] -> U[32][520]
//   [36864,53504): Pt[32][260]
//   [53504,54528): red[256] f32
// -----------------------------------------------------------------------------
__global__ __launch_bounds__(256, 3) void attn_kernel(const u16* __restrict__ h_h,
                                                      const u16* __restrict__ h_l,
                                                      const u16* __restrict__ Mt_h,
                                                      const u16* __restrict__ Mt_l,
                                                      const u16* __restrict__ WVt,
                                                      float* __restrict__ out) {
    __shared__ char SM[54528];
    u16*   Th  = (u16*)SM;                    // [32][260]
    u16*   Tl  = (u16*)(SM + 16640);          // [32][260]
    float* S   = (float*)SM;                  // [256][32]
    u16*   HbT = (u16*)SM;                    // [512][36]
    u16*   U   = (u16*)SM;                    // [32][520]
    u16*   Pt  = (u16*)(SM + 36864);          // [32][260]
    float* red = (float*)(SM + 53504);        // [256]

    const int bid = blockIdx.x;
    const int n   = bid & 7;
    const int b   = (bid >> 3) & 127;
    const int at  = bid >> 10;

    const int tid  = threadIdx.x;
    const int wid  = tid >> 6;
    const int lane = tid & 63;
    const int l15  = lane & 15;
    const int quad = lane >> 4;

    const u16* Mth = Mt_h + (size_t)n * 262144;
    const u16* Mtl = Mt_l + (size_t)n * 262144;
    const u16* Wv  = WVt  + (size_t)n * 262144;
    const size_t hb_base = (size_t)b * NENT * HID;
    const size_t ha_base = hb_base + (size_t)at * 32 * HID;

    const floatx4 z4 = {0.f, 0.f, 0.f, 0.f};
    floatx4 Sacc[8];
    #pragma unroll
    for (int i = 0; i < 8; ++i) Sacc[i] = z4;

    for (int H = 0; H < 2; ++H) {
        // ---------- Phase A: T[:, H*256 + 0..255] ----------
        floatx4 Tacc[8];
        #pragma unroll
        for (int i = 0; i < 8; ++i) Tacc[i] = z4;
        for (int ks = 0; ks < 16; ++ks) {
            const int k = ks * 32 + quad * 8;
            Frag Ah[2], Al[2];
            #pragma unroll
            for (int mt = 0; mt < 2; ++mt) {
                const size_t ro = ha_base + (size_t)(mt * 16 + l15) * HID + k;
                Ah[mt].s = *(const u32x4*)(h_h + ro);
                Al[mt].s = *(const u32x4*)(h_l + ro);
            }
            #pragma unroll
            for (int nt = 0; nt < 4; ++nt) {
                const int d = H * 256 + (wid * 4 + nt) * 16 + l15;
                Frag Bh, Bl;
                Bh.s = *(const u32x4*)(Mth + (size_t)d * HID + k);
                Bl.s = *(const u32x4*)(Mtl + (size_t)d * HID + k);
                #pragma unroll
                for (int mt = 0; mt < 2; ++mt) {
                    floatx4 c = Tacc[mt * 4 + nt];
                    c = __builtin_amdgcn_mfma_f32_16x16x32_bf16(Ah[mt].v, Bh.v, c, 0, 0, 0);
                    c = __builtin_amdgcn_mfma_f32_16x16x32_bf16(Ah[mt].v, Bl.v, c, 0, 0, 0);
                    c = __builtin_amdgcn_mfma_f32_16x16x32_bf16(Al[mt].v, Bh.v, c, 0, 0, 0);
                    Tacc[mt * 4 + nt] = c;
                }
            }
        }
        __syncthreads();   // prior readers of Th/Tl are done
        #pragma unroll
        for (int mt = 0; mt < 2; ++mt)
            #pragma unroll
            for (int nt = 0; nt < 4; ++nt)
                #pragma unroll
                for (int r = 0; r < 4; ++r) {
                    const float v = Tacc[mt * 4 + nt][r];
                    const int a  = mt * 16 + quad * 4 + r;
                    const int dl = (wid * 4 + nt) * 16 + l15;
                    const u16 hi = f2bf(v);
                    Th[a * 260 + dl] = hi;
                    Tl[a * 260 + dl] = f2bf(v - bf2f(hi));
                }
        __syncthreads();
        // ---------- Phase B: S^T += hb[:, half] @ T^T ----------
        for (int ks = 0; ks < 8; ++ks) {
            const int kl = ks * 32 + quad * 8;
            const int kg = H * 256 + kl;
            Frag Ah[4], Al[4];
            #pragma unroll
            for (int mt = 0; mt < 4; ++mt) {
                const size_t ro = hb_base + (size_t)((wid * 4 + mt) * 16 + l15) * HID + kg;
                Ah[mt].s = *(const u32x4*)(h_h + ro);
                Al[mt].s = *(const u32x4*)(h_l + ro);
            }
            #pragma unroll
            for (int nt = 0; nt < 2; ++nt) {
                const int ac = nt * 16 + l15;
                Frag Bh, Bl;
                Bh.p.lo = *(const u32x2*)(Th + ac * 260 + kl);
                Bh.p.hi = *(const u32x2*)(Th + ac * 260 + kl + 4);
                Bl.p.lo = *(const u32x2*)(Tl + ac * 260 + kl);
                Bl.p.hi = *(const u32x2*)(Tl + ac * 260 + kl + 4);
                #pragma unroll
                for (int mt = 0; mt < 4; ++mt) {
                    floatx4 c = Sacc[mt * 2 + nt];
                    c = __builtin_amdgcn_mfma_f32_16x16x32_bf16(Ah[mt].v, Bh.v, c, 0, 0, 0);
                    c = __builtin_amdgcn_mfma_f32_16x16x32_bf16(Ah[mt].v, Bl.v, c, 0, 0, 0);
                    c = __builtin_amdgcn_mfma_f32_16x16x32_bf16(Al[mt].v, Bh.v, c, 0, 0, 0);
                    Sacc[mt * 2 + nt] = c;
                }
            }
        }
    }
    __syncthreads();   // all phase-B reads done; write S over Th/Tl region
    #pragma unroll
    for (int mt = 0; mt < 4; ++mt)
        #pragma unroll
        for (int nt = 0; nt < 2; ++nt)
            #pragma unroll
            for (int r = 0; r < 4; ++r) {
                const int e = (wid * 4 + mt) * 16 + quad * 4 + r;
                const int a = nt * 16 + l15;
                S[e * 32 + a] = Sacc[mt * 2 + nt][r];
            }
    __syncthreads();
    // ---------- Softmax over e per agent (ref: softmax then /(sum+1e-12)) ----------
    {
        const int a   = tid & 31;
        const int seg = tid >> 5;
        float v[32];
        #pragma unroll
        for (int i = 0; i < 32; ++i) v[i] = S[(seg * 32 + i) * 32 + a];
        float mx = v[0];
        #pragma unroll
        for (int i = 1; i < 32; ++i) mx = fmaxf(mx, v[i]);
        red[a * 8 + seg] = mx;
        __syncthreads();
        float gmx = red[a * 8 + 0];
        #pragma unroll
        for (int i = 1; i < 8; ++i) gmx = fmaxf(gmx, red[a * 8 + i]);
        __syncthreads();   // before red reuse
        float s = 0.f;
        #pragma unroll
        for (int i = 0; i < 32; ++i) { v[i] = expf(v[i] - gmx); s += v[i]; }
        red[a * 8 + seg] = s;
        __syncthreads();
        float tot = 0.f;
        #pragma unroll
        for (int i = 0; i < 8; ++i) tot += red[a * 8 + i];
        const float inv = 1.0f / tot;
        #pragma unroll
        for (int i = 0; i < 32; ++i)
            Pt[a * 260 + seg * 32 + i] = f2bf(v[i] * inv);
    }
    __syncthreads();   // Pt ready; S region free
    // ---------- Phase C: U = P @ hb (wave-private hb^T staging) ----------
    floatx4 Uacc[16];
    #pragma unroll
    for (int i = 0; i < 16; ++i) Uacc[i] = z4;
    const int d0w = wid * 128;
    for (int et = 0; et < 8; ++et) {
        {
            const int es = lane & 31;
            const int ds = d0w + (lane >> 5) * 64;
            const size_t rb = hb_base + (size_t)(et * 32 + es) * HID;
            #pragma unroll
            for (int c = 0; c < 8; ++c) {
                const int d = ds + c * 8;
                u32x4 u = *(const u32x4*)(h_h + rb + d);
                HbT[(d + 0) * 36 + es] = (u16)(u[0] & 0xFFFFu);
                HbT[(d + 1) * 36 + es] = (u16)(u[0] >> 16);
                HbT[(d + 2) * 36 + es] = (u16)(u[1] & 0xFFFFu);
                HbT[(d + 3) * 36 + es] = (u16)(u[1] >> 16);
                HbT[(d + 4) * 36 + es] = (u16)(u[2] & 0xFFFFu);
                HbT[(d + 5) * 36 + es] = (u16)(u[2] >> 16);
                HbT[(d + 6) * 36 + es] = (u16)(u[3] & 0xFFFFu);
                HbT[(d + 7) * 36 + es] = (u16)(u[3] >> 16);
            }
        }
        // same-wave LDS ordering: writes complete before reads (lgkmcnt)
        Frag Ap[2];
        #pragma unroll
        for (int mt = 0; mt < 2; ++mt) {
            const int ar = mt * 16 + l15;
            Ap[mt].p.lo = *(const u32x2*)(Pt + ar * 260 + et * 32 + quad * 8);
            Ap[mt].p.hi = *(const u32x2*)(Pt + ar * 260 + et * 32 + quad * 8 + 4);
        }
        #pragma unroll
        for (int dt = 0; dt < 8; ++dt) {
            const int d = d0w + dt * 16 + l15;
            Frag Bf;
            Bf.p.lo = *(const u32x2*)(HbT + d * 36 + quad * 8);
            Bf.p.hi = *(const u32x2*)(HbT + d * 36 + quad * 8 + 4);
            #pragma unroll
            for (int mt = 0; mt < 2; ++mt)
                Uacc[mt * 8 + dt] = __builtin_amdgcn_mfma_f32_16x16x32_bf16(Ap[mt].v, Bf.v, Uacc[mt * 8 + dt], 0, 0, 0);
        }
    }
    __syncthreads();   // all C reads done -> overwrite region with U
    #pragma unroll
    for (int mt = 0; mt < 2; ++mt)
        #pragma unroll
        for (int dt = 0; dt < 8; ++dt)
            #pragma unroll
            for (int r = 0; r < 4; ++r) {
                const int a = mt * 16 + quad * 4 + r;
                const int d = d0w + dt * 16 + l15;
                U[a * 520 + d] = f2bf(Uacc[mt * 8 + dt][r]);
            }
    __syncthreads();
    // ---------- Phase D: z = U @ WVt ----------
    floatx4 Zacc[16];
    #pragma unroll
    for (int i = 0; i < 16; ++i) Zacc[i] = z4;
    for (int ks = 0; ks < 16; ++ks) {
        const int k = ks * 32 + quad * 8;
        Frag Au[2];
        #pragma unroll
        for (int mt = 0; mt < 2; ++mt) {
            Au[mt].p.lo = *(const u32x2*)(U + (mt * 16 + l15) * 520 + k);
            Au[mt].p.hi = *(const u32x2*)(U + (mt * 16 + l15) * 520 + k + 4);
        }
        #pragma unroll
        for (int dt = 0; dt < 8; ++dt) {
            const int dn = (wid * 8 + dt) * 16 + l15;
            Frag Bw;
            Bw.s = *(const u32x4*)(Wv + (size_t)dn * HID + k);
            #pragma unroll
            for (int mt = 0; mt < 2; ++mt)
                Zacc[mt * 8 + dt] = __builtin_amdgcn_mfma_f32_16x16x32_bf16(Au[mt].v, Bw.v, Zacc[mt * 8 + dt], 0, 0, 0);
        }
    }
    float* ob = out + ((size_t)b * NAGENT + at * 32) * HID;
    #pragma unroll
    for (int mt = 0; mt < 2; ++mt)
        #pragma unroll
        for (int dt = 0; dt < 8; ++dt)
            #pragma unroll
            for (int r = 0; r < 4; ++r) {
                const int a  = mt * 16 + quad * 4 + r;
                const int dn = (wid * 8 + dt) * 16 + l15;
                atomicAdd(ob + (size_t)a * HID + dn, Zacc[mt * 8 + dt][r] * 0.125f);
            }
}

// -----------------------------------------------------------------------------
// ws layout (76 MB): h_h 32M | h_l 32M | Mt_h 4M | Mt_l 4M | WVt 4M
// -----------------------------------------------------------------------------
extern "C" void kernel_launch(void* const* d_in, const int* in_sizes, int n_in,
                              void* d_out, int out_size, void* d_ws, size_t ws_size,
                              hipStream_t stream) {
    const float* x     = (const float*)d_in[0];
    const float* W_enc = (const float*)d_in[1];
    const float* b_enc = (const float*)d_in[2];
    const float* WQ    = (const float*)d_in[3];
    const float* WK    = (const float*)d_in[4];
    const float* WV    = (const float*)d_in[5];
    float* out = (float*)d_out;

    char* ws = (char*)d_ws;
    u16* h_h  = (u16*)ws;
    u16* h_l  = (u16*)(ws + 33554432);
    u16* Mt_h = (u16*)(ws + 67108864);
    u16* Mt_l = (u16*)(ws + 71303168);
    u16* WVt  = (u16*)(ws + 75497472);

    hipMemsetAsync(d_out, 0, (size_t)out_size * sizeof(float), stream);
    enc_kernel<<<4096, 256, 0, stream>>>(x, W_enc, b_enc, h_h, h_l);
    wqk_kernel<<<512, 256, 0, stream>>>(WQ, WK, Mt_h, Mt_l);
    wvt_kernel<<<512, 256, 0, stream>>>(WV, WVt);
    attn_kernel<<<2048, 256, 0, stream>>>(h_h, h_l, Mt_h, Mt_l, WVt, out);
}

// Round 3
// 984.220 us; speedup vs baseline: 3.1553x; 1.1323x over previous
//
#include <hip/hip_runtime.h>
#include <math.h>

#define BATCH  128
#define NENT   256
#define INDIM  256
#define HID    512
#define NHEAD  8
#define NAGENT 64
#define SCALE  0.04419417382415922f   // 1/sqrt(512)

typedef unsigned short u16;
typedef unsigned int   u32;

typedef __bf16 bf16x8  __attribute__((ext_vector_type(8)));
typedef float  floatx4 __attribute__((ext_vector_type(4)));
typedef u32    u32x4   __attribute__((ext_vector_type(4)));
typedef u32    u32x2   __attribute__((ext_vector_type(2)));

union Frag {
    u32x4 s;
    struct { u32x2 lo, hi; } p;
    bf16x8 v;
};

__device__ __forceinline__ u16 f2bf(float x) {
    u32 u = __float_as_uint(x);
    return (u16)((u + 0x7FFFu + ((u >> 16) & 1u)) >> 16);
}
__device__ __forceinline__ float bf2f(u16 b) {
    return __uint_as_float(((u32)b) << 16);
}
__device__ __forceinline__ void split4(const float4& r, ushort4& hh, ushort4& hl) {
    hh.x = f2bf(r.x); hl.x = f2bf(r.x - bf2f(hh.x));
    hh.y = f2bf(r.y); hl.y = f2bf(r.y - bf2f(hh.y));
    hh.z = f2bf(r.z); hl.z = f2bf(r.z - bf2f(hh.z));
    hh.w = f2bf(r.w); hl.w = f2bf(r.w - bf2f(hh.w));
}

// -----------------------------------------------------------------------------
// K0: Wt[d][k] = split(W_enc[k][d])  (transpose + bf16 hi/lo), 512x256
// -----------------------------------------------------------------------------
__global__ __launch_bounds__(256) void wenc_t_kernel(const float* __restrict__ W,
                                                     u16* __restrict__ Wt_h,
                                                     u16* __restrict__ Wt_l) {
    __shared__ float tile[64][68];
    const int bid = blockIdx.x;          // 4 k-tiles x 8 d-tiles
    const int k0 = (bid & 3) * 64;
    const int d0 = (bid >> 2) * 64;
    const int t = threadIdx.x;
    const int ki = t >> 2, dc = (t & 3) * 16;
    #pragma unroll
    for (int c = 0; c < 4; ++c)
        *(float4*)&tile[ki][dc + c * 4] =
            *(const float4*)(W + (size_t)(k0 + ki) * HID + d0 + dc + c * 4);
    __syncthreads();
    const int dr = t >> 2, kc = (t & 3) * 16;
    #pragma unroll
    for (int c = 0; c < 4; ++c) {
        float4 v = make_float4(tile[kc + c * 4 + 0][dr], tile[kc + c * 4 + 1][dr],
                               tile[kc + c * 4 + 2][dr], tile[kc + c * 4 + 3][dr]);
        ushort4 hh, hl; split4(v, hh, hl);
        size_t o = (size_t)(d0 + dr) * INDIM + k0 + kc + c * 4;
        *(ushort4*)(Wt_h + o) = hh;
        *(ushort4*)(Wt_l + o) = hl;
    }
}

// -----------------------------------------------------------------------------
// K1: h = leaky_relu(x) @ W_enc + b_enc via split-bf16 3-pass MFMA.
// Block: 32 rows x 512 cols, 4 waves (2 m-tiles x 2 n-halves). grid = 1024.
// -----------------------------------------------------------------------------
__global__ __launch_bounds__(256) void enc_kernel(const float* __restrict__ x,
                                                  const u16* __restrict__ Wt_h,
                                                  const u16* __restrict__ Wt_l,
                                                  const float* __restrict__ bias,
                                                  u16* __restrict__ h_h,
                                                  u16* __restrict__ h_l) {
    __shared__ u16 Ah[32][264];
    __shared__ u16 Al[32][264];
    const int r0 = blockIdx.x * 32;
    const int t  = threadIdx.x;
    {
        const int row = t >> 3;
        const float* xr = x + (size_t)(r0 + row) * INDIM;
        #pragma unroll
        for (int j = 0; j < 8; ++j) {
            const int k0 = ((t & 7) + j * 8) * 4;
            float4 v = *(const float4*)(xr + k0);
            v.x = v.x > 0.f ? v.x : 0.01f * v.x;
            v.y = v.y > 0.f ? v.y : 0.01f * v.y;
            v.z = v.z > 0.f ? v.z : 0.01f * v.z;
            v.w = v.w > 0.f ? v.w : 0.01f * v.w;
            ushort4 hh, hl; split4(v, hh, hl);
            *(ushort4*)&Ah[row][k0] = hh;
            *(ushort4*)&Al[row][k0] = hl;
        }
    }
    __syncthreads();

    const int wid = t >> 6, lane = t & 63, l15 = lane & 15, quad = lane >> 4;
    const int mbase = (wid & 1) * 16;
    const int nbase = (wid >> 1) * 256;
    const floatx4 z4 = {0.f, 0.f, 0.f, 0.f};
    floatx4 acc[16];
    #pragma unroll
    for (int i = 0; i < 16; ++i) acc[i] = z4;

    for (int ks = 0; ks < 8; ++ks) {
        const int k = ks * 32 + quad * 8;
        Frag Afh, Afl;
        Afh.s = *(const u32x4*)&Ah[mbase + l15][k];
        Afl.s = *(const u32x4*)&Al[mbase + l15][k];
        #pragma unroll
        for (int nt = 0; nt < 16; ++nt) {
            const int d = nbase + nt * 16 + l15;
            Frag Bh, Bl;
            Bh.s = *(const u32x4*)(Wt_h + (size_t)d * INDIM + k);
            Bl.s = *(const u32x4*)(Wt_l + (size_t)d * INDIM + k);
            floatx4 c = acc[nt];
            c = __builtin_amdgcn_mfma_f32_16x16x32_bf16(Afh.v, Bh.v, c, 0, 0, 0);
            c = __builtin_amdgcn_mfma_f32_16x16x32_bf16(Afh.v, Bl.v, c, 0, 0, 0);
            c = __builtin_amdgcn_mfma_f32_16x16x32_bf16(Afl.v, Bh.v, c, 0, 0, 0);
            acc[nt] = c;
        }
    }
    #pragma unroll
    for (int nt = 0; nt < 16; ++nt) {
        const int d = nbase + nt * 16 + l15;
        const float bv = bias[d];
        #pragma unroll
        for (int r = 0; r < 4; ++r) {
            const float v = acc[nt][r] + bv;
            const u16 hi = f2bf(v);
            const u16 lo = f2bf(v - bf2f(hi));
            const size_t o = (size_t)(r0 + mbase + quad * 4 + r) * HID + d;
            h_h[o] = hi;
            h_l[o] = lo;
        }
    }
}

// -----------------------------------------------------------------------------
// K2: Mt[n][j][i] = SCALE * dot(WQ[n][i,:], WK[n][j,:]) via split MFMA.
// fp32 -> hi/lo staged in LDS per 64-k chunk. Block 64x64 tile, grid 512.
// -----------------------------------------------------------------------------
__global__ __launch_bounds__(256) void wqk_kernel(const float* __restrict__ WQ,
                                                  const float* __restrict__ WK,
                                                  u16* __restrict__ Mt_h,
                                                  u16* __restrict__ Mt_l) {
    __shared__ u16 Ah[64][72], Al[64][72], Bh[64][72], Bl[64][72];
    const int bid = blockIdx.x;
    const int jt = (bid & 7) * 64;
    const int it = ((bid >> 3) & 7) * 64;
    const int n  = bid >> 6;
    const float* qp = WQ + (size_t)n * 262144;
    const float* kp = WK + (size_t)n * 262144;
    const int t = threadIdx.x;
    const int wid = t >> 6, lane = t & 63, l15 = lane & 15, quad = lane >> 4;
    const int srow = t >> 2, sc = (t & 3) * 16;

    const floatx4 z4 = {0.f, 0.f, 0.f, 0.f};
    floatx4 acc[4];
    #pragma unroll
    for (int i = 0; i < 4; ++i) acc[i] = z4;

    for (int kc = 0; kc < HID; kc += 64) {
        #pragma unroll
        for (int f = 0; f < 4; ++f) {
            float4 va = *(const float4*)(kp + (size_t)(jt + srow) * HID + kc + sc + f * 4);
            ushort4 hh, hl; split4(va, hh, hl);
            *(ushort4*)&Ah[srow][sc + f * 4] = hh;
            *(ushort4*)&Al[srow][sc + f * 4] = hl;
            float4 vb = *(const float4*)(qp + (size_t)(it + srow) * HID + kc + sc + f * 4);
            split4(vb, hh, hl);
            *(ushort4*)&Bh[srow][sc + f * 4] = hh;
            *(ushort4*)&Bl[srow][sc + f * 4] = hl;
        }
        __syncthreads();
        #pragma unroll
        for (int ks = 0; ks < 2; ++ks) {
            const int k = ks * 32 + quad * 8;
            Frag Afh, Afl;
            Afh.s = *(const u32x4*)&Ah[wid * 16 + l15][k];
            Afl.s = *(const u32x4*)&Al[wid * 16 + l15][k];
            #pragma unroll
            for (int nt = 0; nt < 4; ++nt) {
                Frag Bfh, Bfl;
                Bfh.s = *(const u32x4*)&Bh[nt * 16 + l15][k];
                Bfl.s = *(const u32x4*)&Bl[nt * 16 + l15][k];
                floatx4 c = acc[nt];
                c = __builtin_amdgcn_mfma_f32_16x16x32_bf16(Afh.v, Bfh.v, c, 0, 0, 0);
                c = __builtin_amdgcn_mfma_f32_16x16x32_bf16(Afh.v, Bfl.v, c, 0, 0, 0);
                c = __builtin_amdgcn_mfma_f32_16x16x32_bf16(Afl.v, Bfh.v, c, 0, 0, 0);
                acc[nt] = c;
            }
        }
        __syncthreads();
    }
    #pragma unroll
    for (int nt = 0; nt < 4; ++nt)
        #pragma unroll
        for (int r = 0; r < 4; ++r) {
            const float v = acc[nt][r] * SCALE;
            const u16 hi = f2bf(v);
            const u16 lo = f2bf(v - bf2f(hi));
            const int j = jt + wid * 16 + quad * 4 + r;
            const int i = it + nt * 16 + l15;
            const size_t o = (size_t)n * 262144 + (size_t)j * HID + i;
            Mt_h[o] = hi;
            Mt_l[o] = lo;
        }
}

// -----------------------------------------------------------------------------
// K3: WVt[n][dout][din] = bf16(WV[n][din][dout])
// -----------------------------------------------------------------------------
__global__ __launch_bounds__(256) void wvt_kernel(const float* __restrict__ WV,
                                                  u16* __restrict__ WVt) {
    __shared__ float tile[64][68];
    const int bid = blockIdx.x;
    const int i0 = (bid & 7) * 64;
    const int o0 = ((bid >> 3) & 7) * 64;
    const int n  = bid >> 6;
    const float* src = WV + (size_t)n * 262144;
    const int t  = threadIdx.x;
    const int di = t >> 2;
    const int dc = (t & 3) * 16;
    #pragma unroll
    for (int c = 0; c < 4; ++c)
        *(float4*)&tile[di][dc + c * 4] =
            *(const float4*)(src + (size_t)(i0 + di) * HID + o0 + dc + c * 4);
    __syncthreads();
    const int dr = t >> 2;
    const int ic = (t & 3) * 16;
    size_t o = (size_t)n * 262144 + (size_t)(o0 + dr) * HID + i0 + ic;
    #pragma unroll
    for (int c = 0; c < 4; ++c) {
        ushort4 v = make_ushort4(f2bf(tile[ic + c * 4 + 0][dr]), f2bf(tile[ic + c * 4 + 1][dr]),
                                 f2bf(tile[ic + c * 4 + 2][dr]), f2bf(tile[ic + c * 4 + 3][dr]));
        *(ushort4*)(WVt + o + c * 4) = v;
    }
}

// -----------------------------------------------------------------------------
// K4: fused MFMA attention. LDS 53504 B -> 3 blocks/CU.
//   region1 [0,36864): Th[32][260]+Tl | S[256][33]f32 + red@33792 | HbT[512][36] | U[32][520]
//   Pt @36864: [32][260]
// Swizzle: XCD = 2 heads x (b&1); same-b quad (2n x 2at) adjacent.
// -----------------------------------------------------------------------------
__global__ __launch_bounds__(256, 3) void attn_kernel(const u16* __restrict__ h_h,
                                                      const u16* __restrict__ h_l,
                                                      const u16* __restrict__ Mt_h,
                                                      const u16* __restrict__ Mt_l,
                                                      const u16* __restrict__ WVt,
                                                      float* __restrict__ out) {
    __shared__ __align__(16) char SM[53504];
    u16*   Th  = (u16*)SM;                    // [32][260]
    u16*   Tl  = (u16*)(SM + 16640);          // [32][260]
    float* S   = (float*)SM;                  // [256][33]
    float* red = (float*)(SM + 33792);        // [256]
    u16*   HbT = (u16*)SM;                    // [512][36]
    u16*   U   = (u16*)SM;                    // [32][520]
    u16*   Pt  = (u16*)(SM + 36864);          // [32][260]

    const int bid = blockIdx.x;
    const int x7 = bid & 7;
    const int s  = bid >> 3;
    const int at = s & 1;
    const int n  = (x7 >> 1) | (((s >> 1) & 1) << 2);
    const int b  = ((s >> 2) << 1) | (x7 & 1);

    const int tid  = threadIdx.x;
    const int wid  = tid >> 6;
    const int lane = tid & 63;
    const int l15  = lane & 15;
    const int quad = lane >> 4;

    const u16* Mth = Mt_h + (size_t)n * 262144;
    const u16* Mtl = Mt_l + (size_t)n * 262144;
    const u16* Wv  = WVt  + (size_t)n * 262144;
    const size_t hb_base = (size_t)b * NENT * HID;
    const size_t ha_base = hb_base + (size_t)at * 32 * HID;

    const floatx4 z4 = {0.f, 0.f, 0.f, 0.f};
    floatx4 Sacc[8];
    #pragma unroll
    for (int i = 0; i < 8; ++i) Sacc[i] = z4;

    for (int H = 0; H < 2; ++H) {
        // ---------- Phase A: T[:, H*256 + 0..255] ----------
        floatx4 Tacc[8];
        #pragma unroll
        for (int i = 0; i < 8; ++i) Tacc[i] = z4;
        for (int ks = 0; ks < 16; ++ks) {
            const int k = ks * 32 + quad * 8;
            Frag Ahf[2], Alf[2];
            #pragma unroll
            for (int mt = 0; mt < 2; ++mt) {
                const size_t ro = ha_base + (size_t)(mt * 16 + l15) * HID + k;
                Ahf[mt].s = *(const u32x4*)(h_h + ro);
                Alf[mt].s = *(const u32x4*)(h_l + ro);
            }
            #pragma unroll
            for (int nt = 0; nt < 4; ++nt) {
                const int d = H * 256 + (wid * 4 + nt) * 16 + l15;
                Frag Bh, Bl;
                Bh.s = *(const u32x4*)(Mth + (size_t)d * HID + k);
                Bl.s = *(const u32x4*)(Mtl + (size_t)d * HID + k);
                #pragma unroll
                for (int mt = 0; mt < 2; ++mt) {
                    floatx4 c = Tacc[mt * 4 + nt];
                    c = __builtin_amdgcn_mfma_f32_16x16x32_bf16(Ahf[mt].v, Bh.v, c, 0, 0, 0);
                    c = __builtin_amdgcn_mfma_f32_16x16x32_bf16(Ahf[mt].v, Bl.v, c, 0, 0, 0);
                    c = __builtin_amdgcn_mfma_f32_16x16x32_bf16(Alf[mt].v, Bh.v, c, 0, 0, 0);
                    Tacc[mt * 4 + nt] = c;
                }
            }
        }
        __syncthreads();
        #pragma unroll
        for (int mt = 0; mt < 2; ++mt)
            #pragma unroll
            for (int nt = 0; nt < 4; ++nt)
                #pragma unroll
                for (int r = 0; r < 4; ++r) {
                    const float v = Tacc[mt * 4 + nt][r];
                    const int a  = mt * 16 + quad * 4 + r;
                    const int dl = (wid * 4 + nt) * 16 + l15;
                    const u16 hi = f2bf(v);
                    Th[a * 260 + dl] = hi;
                    Tl[a * 260 + dl] = f2bf(v - bf2f(hi));
                }
        __syncthreads();
        // ---------- Phase B: S^T += hb[:, half] @ T^T ----------
        for (int ks = 0; ks < 8; ++ks) {
            const int kl = ks * 32 + quad * 8;
            const int kg = H * 256 + kl;
            Frag Ahf[4], Alf[4];
            #pragma unroll
            for (int mt = 0; mt < 4; ++mt) {
                const size_t ro = hb_base + (size_t)((wid * 4 + mt) * 16 + l15) * HID + kg;
                Ahf[mt].s = *(const u32x4*)(h_h + ro);
                Alf[mt].s = *(const u32x4*)(h_l + ro);
            }
            #pragma unroll
            for (int nt = 0; nt < 2; ++nt) {
                const int ac = nt * 16 + l15;
                Frag Bh, Bl;
                Bh.p.lo = *(const u32x2*)(Th + ac * 260 + kl);
                Bh.p.hi = *(const u32x2*)(Th + ac * 260 + kl + 4);
                Bl.p.lo = *(const u32x2*)(Tl + ac * 260 + kl);
                Bl.p.hi = *(const u32x2*)(Tl + ac * 260 + kl + 4);
                #pragma unroll
                for (int mt = 0; mt < 4; ++mt) {
                    floatx4 c = Sacc[mt * 2 + nt];
                    c = __builtin_amdgcn_mfma_f32_16x16x32_bf16(Ahf[mt].v, Bh.v, c, 0, 0, 0);
                    c = __builtin_amdgcn_mfma_f32_16x16x32_bf16(Ahf[mt].v, Bl.v, c, 0, 0, 0);
                    c = __builtin_amdgcn_mfma_f32_16x16x32_bf16(Alf[mt].v, Bh.v, c, 0, 0, 0);
                    Sacc[mt * 2 + nt] = c;
                }
            }
        }
    }
    __syncthreads();
    #pragma unroll
    for (int mt = 0; mt < 4; ++mt)
        #pragma unroll
        for (int nt = 0; nt < 2; ++nt)
            #pragma unroll
            for (int r = 0; r < 4; ++r) {
                const int e = (wid * 4 + mt) * 16 + quad * 4 + r;
                const int a = nt * 16 + l15;
                S[e * 33 + a] = Sacc[mt * 2 + nt][r];
            }
    __syncthreads();
    // ---------- Softmax over e per agent ----------
    {
        const int a   = tid & 31;
        const int seg = tid >> 5;
        float v[32];
        #pragma unroll
        for (int i = 0; i < 32; ++i) v[i] = S[(seg * 32 + i) * 33 + a];
        float mx = v[0];
        #pragma unroll
        for (int i = 1; i < 32; ++i) mx = fmaxf(mx, v[i]);
        red[a * 8 + seg] = mx;
        __syncthreads();
        float gmx = red[a * 8 + 0];
        #pragma unroll
        for (int i = 1; i < 8; ++i) gmx = fmaxf(gmx, red[a * 8 + i]);
        __syncthreads();
        float sum = 0.f;
        #pragma unroll
        for (int i = 0; i < 32; ++i) { v[i] = expf(v[i] - gmx); sum += v[i]; }
        red[a * 8 + seg] = sum;
        __syncthreads();
        float tot = 0.f;
        #pragma unroll
        for (int i = 0; i < 8; ++i) tot += red[a * 8 + i];
        const float inv = 1.0f / tot;
        #pragma unroll
        for (int i = 0; i < 32; ++i)
            Pt[a * 260 + seg * 32 + i] = f2bf(v[i] * inv);
    }
    __syncthreads();
    // ---------- Phase C: U = P @ hb (pair-packed hb^T staging, wave-private) ----------
    floatx4 Uacc[16];
    #pragma unroll
    for (int i = 0; i < 16; ++i) Uacc[i] = z4;
    const int d0w = wid * 128;
    u32* Hb32 = (u32*)HbT;
    for (int et = 0; et < 8; ++et) {
        {
            const int ep = lane & 15;
            const int q  = lane >> 4;
            const size_t r0 = hb_base + (size_t)(et * 32 + 2 * ep) * HID;
            #pragma unroll
            for (int c = 0; c < 4; ++c) {
                const int d0 = d0w + c * 32 + q * 8;
                u32x4 u0 = *(const u32x4*)(h_h + r0 + d0);
                u32x4 u1 = *(const u32x4*)(h_h + r0 + HID + d0);
                #pragma unroll
                for (int p = 0; p < 4; ++p) {
                    const u32 w0 = (u0[p] & 0xFFFFu) | (u1[p] << 16);
                    const u32 w1 = (u0[p] >> 16) | (u1[p] & 0xFFFF0000u);
                    Hb32[(d0 + 2 * p) * 18 + ep]     = w0;
                    Hb32[(d0 + 2 * p + 1) * 18 + ep] = w1;
                }
            }
        }
        Frag Ap[2];
        #pragma unroll
        for (int mt = 0; mt < 2; ++mt) {
            const int ar = mt * 16 + l15;
            Ap[mt].p.lo = *(const u32x2*)(Pt + ar * 260 + et * 32 + quad * 8);
            Ap[mt].p.hi = *(const u32x2*)(Pt + ar * 260 + et * 32 + quad * 8 + 4);
        }
        #pragma unroll
        for (int dt = 0; dt < 8; ++dt) {
            const int d = d0w + dt * 16 + l15;
            Frag Bf;
            Bf.p.lo = *(const u32x2*)(HbT + d * 36 + quad * 8);
            Bf.p.hi = *(const u32x2*)(HbT + d * 36 + quad * 8 + 4);
            #pragma unroll
            for (int mt = 0; mt < 2; ++mt)
                Uacc[mt * 8 + dt] = __builtin_amdgcn_mfma_f32_16x16x32_bf16(Ap[mt].v, Bf.v, Uacc[mt * 8 + dt], 0, 0, 0);
        }
    }
    __syncthreads();
    #pragma unroll
    for (int mt = 0; mt < 2; ++mt)
        #pragma unroll
        for (int dt = 0; dt < 8; ++dt)
            #pragma unroll
            for (int r = 0; r < 4; ++r) {
                const int a = mt * 16 + quad * 4 + r;
                const int d = d0w + dt * 16 + l15;
                U[a * 520 + d] = f2bf(Uacc[mt * 8 + dt][r]);
            }
    __syncthreads();
    // ---------- Phase D: z = U @ WVt ----------
    floatx4 Zacc[16];
    #pragma unroll
    for (int i = 0; i < 16; ++i) Zacc[i] = z4;
    for (int ks = 0; ks < 16; ++ks) {
        const int k = ks * 32 + quad * 8;
        Frag Au[2];
        #pragma unroll
        for (int mt = 0; mt < 2; ++mt) {
            Au[mt].p.lo = *(const u32x2*)(U + (mt * 16 + l15) * 520 + k);
            Au[mt].p.hi = *(const u32x2*)(U + (mt * 16 + l15) * 520 + k + 4);
        }
        #pragma unroll
        for (int dt = 0; dt < 8; ++dt) {
            const int dn = (wid * 8 + dt) * 16 + l15;
            Frag Bw;
            Bw.s = *(const u32x4*)(Wv + (size_t)dn * HID + k);
            #pragma unroll
            for (int mt = 0; mt < 2; ++mt)
                Zacc[mt * 8 + dt] = __builtin_amdgcn_mfma_f32_16x16x32_bf16(Au[mt].v, Bw.v, Zacc[mt * 8 + dt], 0, 0, 0);
        }
    }
    float* ob = out + ((size_t)b * NAGENT + at * 32) * HID;
    #pragma unroll
    for (int mt = 0; mt < 2; ++mt)
        #pragma unroll
        for (int dt = 0; dt < 8; ++dt)
            #pragma unroll
            for (int r = 0; r < 4; ++r) {
                const int a  = mt * 16 + quad * 4 + r;
                const int dn = (wid * 8 + dt) * 16 + l15;
                atomicAdd(ob + (size_t)a * HID + dn, Zacc[mt * 8 + dt][r] * 0.125f);
            }
}

// -----------------------------------------------------------------------------
// ws layout (76 MB, proven): h_h 32M | h_l 32M | Mt_h 4M | Mt_l 4M | WVt 4M.
// Wt (enc weights, 1 MB) transiently lives in the WVt region: wenc_t -> enc
// -> wvt (overwrites) -> wqk -> attn, all stream-ordered.
// -----------------------------------------------------------------------------
extern "C" void kernel_launch(void* const* d_in, const int* in_sizes, int n_in,
                              void* d_out, int out_size, void* d_ws, size_t ws_size,
                              hipStream_t stream) {
    const float* x     = (const float*)d_in[0];
    const float* W_enc = (const float*)d_in[1];
    const float* b_enc = (const float*)d_in[2];
    const float* WQ    = (const float*)d_in[3];
    const float* WK    = (const float*)d_in[4];
    const float* WV    = (const float*)d_in[5];
    float* out = (float*)d_out;

    char* ws = (char*)d_ws;
    u16* h_h  = (u16*)ws;
    u16* h_l  = (u16*)(ws + 33554432);
    u16* Mt_h = (u16*)(ws + 67108864);
    u16* Mt_l = (u16*)(ws + 71303168);
    u16* WVt  = (u16*)(ws + 75497472);
    u16* Wt_h = WVt;                       // transient, 256 KB
    u16* Wt_l = WVt + 131072;              // transient, 256 KB

    hipMemsetAsync(d_out, 0, (size_t)out_size * sizeof(float), stream);
    wenc_t_kernel<<<32, 256, 0, stream>>>(W_enc, Wt_h, Wt_l);
    enc_kernel<<<1024, 256, 0, stream>>>(x, Wt_h, Wt_l, b_enc, h_h, h_l);
    wvt_kernel<<<512, 256, 0, stream>>>(WV, WVt);
    wqk_kernel<<<512, 256, 0, stream>>>(WQ, WK, Mt_h, Mt_l);
    attn_kernel<<<2048, 256, 0, stream>>>(h_h, h_l, Mt_h, Mt_l, WVt, out);
}